// Round 1
// baseline (5718.026 us; speedup 1.0000x reference)
//
#include <hip/hip_runtime.h>

// SGC: x:(N,128) f32, edge_index:(2,E) i32, edge_weight:(E,) f32,
// weight:(128,128) f32, bias:(128,) f32.  out:(N,128) f32.
// h <- A_hat @ h (2 hops), out = h @ W^T + b.

constexpr int D = 128;

__global__ void zero_kernel(float* p, int n) {
    int i = blockIdx.x * blockDim.x + threadIdx.x;
    if (i < n) p[i] = 0.0f;
}

// deg[col[e]] += ew[e]
__global__ void deg_kernel(const int* __restrict__ col, const float* __restrict__ ew,
                           float* __restrict__ deg, int E) {
    int e = blockIdx.x * blockDim.x + threadIdx.x;
    if (e < E) atomicAdd(&deg[col[e]], ew[e]);
}

// dinv = rsqrt(deg + 1)   (+1 = self-loop weight; always > 0)
__global__ void dinv_kernel(float* __restrict__ deg, int n) {
    int i = blockIdx.x * blockDim.x + threadIdx.x;
    if (i < n) deg[i] = rsqrtf(deg[i] + 1.0f);
}

// out = dinv^2 * h  (self-loop contribution; also fully initializes out)
__global__ void hop_init_kernel(const float* __restrict__ h, const float* __restrict__ dinv,
                                float* __restrict__ out, int nvec) {
    int t = blockIdx.x * blockDim.x + threadIdx.x;  // nvec = N*D/4
    if (t >= nvec) return;
    int node = t / (D / 4);
    float s = dinv[node];
    s = s * s;
    float4 v = reinterpret_cast<const float4*>(h)[t];
    v.x *= s; v.y *= s; v.z *= s; v.w *= s;
    reinterpret_cast<float4*>(out)[t] = v;
}

// out[col] += dinv[row]*ew*dinv[col] * h[row]; 32 threads per edge, float4 each
__global__ void hop_scatter_kernel(const int* __restrict__ row, const int* __restrict__ col,
                                   const float* __restrict__ ew, const float* __restrict__ dinv,
                                   const float* __restrict__ h, float* __restrict__ out, int E) {
    long long t = (long long)blockIdx.x * blockDim.x + threadIdx.x;
    int e = (int)(t >> 5);
    int c = (int)(t & 31);
    if (e >= E) return;
    int r = row[e];
    int cl = col[e];
    float nw = dinv[r] * ew[e] * dinv[cl];
    float4 v = reinterpret_cast<const float4*>(h + (size_t)r * D)[c];
    float* dst = out + (size_t)cl * D + (size_t)c * 4;
    atomicAdd(dst + 0, nw * v.x);
    atomicAdd(dst + 1, nw * v.y);
    atomicAdd(dst + 2, nw * v.z);
    atomicAdd(dst + 3, nw * v.w);
}

// In-place per-row linear: io[r,:] = W @ io[r,:] + bias. 16 rows / block.
#define LROWS 16
__global__ __launch_bounds__(256) void linear_kernel(const float* __restrict__ W,
                                                     const float* __restrict__ bias,
                                                     float* __restrict__ io, int nrows) {
    __shared__ float Wl[D][D + 1];   // +1 pad: bank = (j+d)%32 -> 2-way (free)
    __shared__ float Hl[LROWS][D];
    int tid = threadIdx.x;
    for (int i = tid; i < D * D; i += 256) {
        Wl[i / D][i % D] = W[i];
    }
    int base = blockIdx.x * LROWS;
    for (int i = tid; i < LROWS * D; i += 256) {
        int r = i / D, d = i % D;
        int node = base + r;
        Hl[r][d] = (node < nrows) ? io[(size_t)node * D + d] : 0.0f;
    }
    __syncthreads();
    int j = tid % D;       // output feature
    int r0 = tid / D;      // 0..1
    for (int r = r0; r < LROWS; r += 2) {
        float acc = bias[j];
        #pragma unroll 8
        for (int d = 0; d < D; ++d) acc += Wl[j][d] * Hl[r][d];
        int node = base + r;
        if (node < nrows) io[(size_t)node * D + j] = acc;
    }
}

extern "C" void kernel_launch(void* const* d_in, const int* in_sizes, int n_in,
                              void* d_out, int out_size, void* d_ws, size_t ws_size,
                              hipStream_t stream) {
    const float* x      = (const float*)d_in[0];
    const int*   eidx   = (const int*)d_in[1];
    const float* ew     = (const float*)d_in[2];
    const float* W      = (const float*)d_in[3];
    const float* bias   = (const float*)d_in[4];
    float* out = (float*)d_out;

    const int N = in_sizes[0] / D;       // 100000
    const int E = in_sizes[2];           // 1600000
    const int* erow = eidx;              // edge_index[0] = source
    const int* ecol = eidx + E;          // edge_index[1] = target

    // ws layout: dinv [N floats] | h1 [N*D floats]
    float* dinv = (float*)d_ws;
    float* h1   = dinv + N;

    const int B = 256;

    // 1. degree + dinv
    zero_kernel<<<(N + B - 1) / B, B, 0, stream>>>(dinv, N);
    deg_kernel<<<(E + B - 1) / B, B, 0, stream>>>(ecol, ew, dinv, E);
    dinv_kernel<<<(N + B - 1) / B, B, 0, stream>>>(dinv, N);

    const int nvec = N * D / 4;
    const long long scat_threads = (long long)E * 32;
    const int scat_blocks = (int)((scat_threads + B - 1) / B);

    // 2. hop 1: h1 = A_hat @ x
    hop_init_kernel<<<(nvec + B - 1) / B, B, 0, stream>>>(x, dinv, h1, nvec);
    hop_scatter_kernel<<<scat_blocks, B, 0, stream>>>(erow, ecol, ew, dinv, x, h1, E);

    // 3. hop 2: out = A_hat @ h1
    hop_init_kernel<<<(nvec + B - 1) / B, B, 0, stream>>>(h1, dinv, out, nvec);
    hop_scatter_kernel<<<scat_blocks, B, 0, stream>>>(erow, ecol, ew, dinv, h1, out, E);

    // 4. out = out @ W^T + bias  (in place)
    linear_kernel<<<(N + LROWS - 1) / LROWS, 256, 0, stream>>>(W, bias, out, N);
}

// Round 2
// 790.953 us; speedup vs baseline: 7.2293x; 7.2293x over previous
//
#include <hip/hip_runtime.h>

// SGC: x:(N,128) f32, edge_index:(2,E) i32, edge_weight:(E,) f32,
// weight:(128,128) f32, bias:(128,) f32.  out:(N,128) f32.
// h <- A_hat @ h (2 hops), out = h @ W^T + b.
// Strategy: build CSR-by-target on device, gather-accumulate (no output atomics).

constexpr int D = 128;

__global__ void zero_f(float* p, int n) {
    int i = blockIdx.x * blockDim.x + threadIdx.x;
    if (i < n) p[i] = 0.0f;
}
__global__ void zero_i(int* p, int n) {
    int i = blockIdx.x * blockDim.x + threadIdx.x;
    if (i < n) p[i] = 0;
}

// degf[c] += ew[e]; degi[c] += 1
__global__ void count_kernel(const int* __restrict__ col, const float* __restrict__ ew,
                             float* __restrict__ degf, int* __restrict__ degi, int E) {
    int e = blockIdx.x * blockDim.x + threadIdx.x;
    if (e >= E) return;
    int c = col[e];
    atomicAdd(&degf[c], ew[e]);
    atomicAdd(&degi[c], 1);
}

// dinv = rsqrt(degf + 1)   (+1 = self-loop weight; always > 0)
__global__ void dinv_kernel(float* __restrict__ degf, int n) {
    int i = blockIdx.x * blockDim.x + threadIdx.x;
    if (i < n) degf[i] = rsqrtf(degf[i] + 1.0f);
}

// ---- exclusive scan of degi -> rowptr (3 tiny kernels, 1024 elems/block) ----
__global__ __launch_bounds__(256) void scan_bsum(const int* __restrict__ degi,
                                                 int* __restrict__ bsum, int n) {
    int base = blockIdx.x * 1024;
    int t = threadIdx.x;
    int s = 0;
    #pragma unroll
    for (int k = 0; k < 4; ++k) { int i = base + t * 4 + k; if (i < n) s += degi[i]; }
    __shared__ int sh[256];
    sh[t] = s; __syncthreads();
    for (int off = 128; off > 0; off >>= 1) {
        if (t < off) sh[t] += sh[t + off];
        __syncthreads();
    }
    if (t == 0) bsum[blockIdx.x] = sh[0];
}

__global__ void scan_exclusive_bsum(int* bsum, int nb) {
    if (blockIdx.x == 0 && threadIdx.x == 0) {
        int run = 0;
        for (int i = 0; i < nb; ++i) { int v = bsum[i]; bsum[i] = run; run += v; }
    }
}

__global__ __launch_bounds__(256) void scan_write_rowptr(const int* __restrict__ degi,
                                                         const int* __restrict__ bsum,
                                                         int* __restrict__ rowptr, int n, int E) {
    int base = blockIdx.x * 1024;
    int t = threadIdx.x;
    int v[4]; int s = 0;
    #pragma unroll
    for (int k = 0; k < 4; ++k) { int i = base + t * 4 + k; v[k] = (i < n) ? degi[i] : 0; s += v[k]; }
    __shared__ int sh[256];
    sh[t] = s; __syncthreads();
    for (int off = 1; off < 256; off <<= 1) {   // Hillis-Steele inclusive
        int x = (t >= off) ? sh[t - off] : 0;
        __syncthreads();
        sh[t] += x;
        __syncthreads();
    }
    int pre = bsum[blockIdx.x] + ((t > 0) ? sh[t - 1] : 0);
    #pragma unroll
    for (int k = 0; k < 4; ++k) { int i = base + t * 4 + k; if (i < n) rowptr[i] = pre; pre += v[k]; }
    if (blockIdx.x == 0 && t == 0) rowptr[n] = E;
}

// bin edges into CSR; precompute norm weight
__global__ void bin_kernel(const int* __restrict__ row, const int* __restrict__ col,
                           const float* __restrict__ ew, const float* __restrict__ dinv,
                           const int* __restrict__ rowptr, int* __restrict__ cursor,
                           int* __restrict__ csr_src, float* __restrict__ csr_w, int E) {
    int e = blockIdx.x * blockDim.x + threadIdx.x;
    if (e >= E) return;
    int r = row[e], c = col[e];
    int pos = rowptr[c] + atomicAdd(&cursor[c], 1);
    csr_src[pos] = r;
    csr_w[pos] = dinv[r] * ew[e] * dinv[c];
}

// one wave per target node: acc(float2/lane) = dinv[n]^2*h[n] + sum_e w_e * h[src_e]
__global__ __launch_bounds__(256) void hop_gather_kernel(
    const int* __restrict__ rowptr, const int* __restrict__ csr_src,
    const float* __restrict__ csr_w, const float* __restrict__ dinv,
    const float* __restrict__ h, float* __restrict__ out, int N) {
    int wave = (int)((blockIdx.x * (long long)blockDim.x + threadIdx.x) >> 6);
    int lane = threadIdx.x & 63;
    if (wave >= N) return;
    const int n = wave;
    int beg = rowptr[n], end = rowptr[n + 1];
    float s = dinv[n];
    float2 v0 = *reinterpret_cast<const float2*>(h + (size_t)n * D + lane * 2);
    float2 acc = make_float2(s * s * v0.x, s * s * v0.y);
    for (int base = beg; base < end; base += 64) {
        int cnt = min(64, end - base);
        int src = 0; float w = 0.0f;
        if (lane < cnt) { src = csr_src[base + lane]; w = csr_w[base + lane]; }
        for (int j = 0; j < cnt; ++j) {
            int  sj = __shfl(src, j);
            float wj = __shfl(w, j);
            float2 hv = *reinterpret_cast<const float2*>(h + (size_t)sj * D + lane * 2);
            acc.x += wj * hv.x;
            acc.y += wj * hv.y;
        }
    }
    *reinterpret_cast<float2*>(out + (size_t)n * D + lane * 2) = acc;
}

// In-place per-row linear: io[r,:] = W @ io[r,:] + bias. 16 rows / block.
#define LROWS 16
__global__ __launch_bounds__(256) void linear_kernel(const float* __restrict__ W,
                                                     const float* __restrict__ bias,
                                                     float* __restrict__ io, int nrows) {
    __shared__ float Wl[D][D + 1];   // +1 pad: 2-way bank alias (free)
    __shared__ float Hl[LROWS][D];
    int tid = threadIdx.x;
    for (int i = tid; i < D * D; i += 256) Wl[i / D][i % D] = W[i];
    int base = blockIdx.x * LROWS;
    for (int i = tid; i < LROWS * D; i += 256) {
        int r = i / D, d = i % D;
        int node = base + r;
        Hl[r][d] = (node < nrows) ? io[(size_t)node * D + d] : 0.0f;
    }
    __syncthreads();
    int j = tid % D;
    int r0 = tid / D;
    for (int r = r0; r < LROWS; r += 2) {
        float acc = bias[j];
        #pragma unroll 8
        for (int d = 0; d < D; ++d) acc += Wl[j][d] * Hl[r][d];
        int node = base + r;
        if (node < nrows) io[(size_t)node * D + j] = acc;
    }
}

extern "C" void kernel_launch(void* const* d_in, const int* in_sizes, int n_in,
                              void* d_out, int out_size, void* d_ws, size_t ws_size,
                              hipStream_t stream) {
    const float* x    = (const float*)d_in[0];
    const int*   eidx = (const int*)d_in[1];
    const float* ew   = (const float*)d_in[2];
    const float* W    = (const float*)d_in[3];
    const float* bias = (const float*)d_in[4];
    float* out = (float*)d_out;

    const int N = in_sizes[0] / D;       // 100000
    const int E = in_sizes[2];           // 1600000
    const int* erow = eidx;              // sources
    const int* ecol = eidx + E;          // targets

    // ws layout (4B units): h1[N*D] | csr_src[E] | csr_w[E] | dinv[N] | degi[N] |
    //                       rowptr[N+1] | cursor[N] | bsum[ceil(N/1024)]
    float* h1      = (float*)d_ws;
    int*   csr_src = (int*)(h1 + (size_t)N * D);
    float* csr_w   = (float*)(csr_src + E);
    float* dinv    = csr_w + E;
    int*   degi    = (int*)(dinv + N);
    int*   rowptr  = degi + N;
    int*   cursor  = rowptr + N + 1;
    int*   bsum    = cursor + N;

    const int B = 256;
    const int nb_scan = (N + 1023) / 1024;

    // 1. degree (weighted + count), dinv
    zero_f<<<(N + B - 1) / B, B, 0, stream>>>(dinv, N);       // dinv doubles as degf
    zero_i<<<(N + B - 1) / B, B, 0, stream>>>(degi, N);
    zero_i<<<(N + B - 1) / B, B, 0, stream>>>(cursor, N);
    count_kernel<<<(E + B - 1) / B, B, 0, stream>>>(ecol, ew, dinv, degi, E);
    dinv_kernel<<<(N + B - 1) / B, B, 0, stream>>>(dinv, N);

    // 2. rowptr = exclusive_scan(degi)
    scan_bsum<<<nb_scan, 256, 0, stream>>>(degi, bsum, N);
    scan_exclusive_bsum<<<1, 1, 0, stream>>>(bsum, nb_scan);
    scan_write_rowptr<<<nb_scan, 256, 0, stream>>>(degi, bsum, rowptr, N, E);

    // 3. bin edges (also precompute norm weights)
    bin_kernel<<<(E + B - 1) / B, B, 0, stream>>>(erow, ecol, ew, dinv, rowptr, cursor,
                                                  csr_src, csr_w, E);

    // 4. hop 1: h1 = A_hat @ x ; hop 2: out = A_hat @ h1
    const int gblocks = (N * 64 + B - 1) / B;
    hop_gather_kernel<<<gblocks, B, 0, stream>>>(rowptr, csr_src, csr_w, dinv, x, h1, N);
    hop_gather_kernel<<<gblocks, B, 0, stream>>>(rowptr, csr_src, csr_w, dinv, h1, out, N);

    // 5. out = out @ W^T + bias (in place)
    linear_kernel<<<(N + LROWS - 1) / LROWS, 256, 0, stream>>>(W, bias, out, N);
}

// Round 3
// 653.939 us; speedup vs baseline: 8.7440x; 1.2095x over previous
//
#include <hip/hip_runtime.h>

// SGC: out = A_hat^2 (x @ W^T) + bias   (linear commutes with propagation)
// 1) y = x @ W^T          (GEMM, y lives in d_out as scratch)
// 2) h1 = A_hat y         (CSR gather, no atomics)
// 3) out = A_hat h1 + b   (CSR gather, bias fused)

constexpr int D = 128;

__global__ void zero_f(float* p, int n) {
    int i = blockIdx.x * blockDim.x + threadIdx.x;
    if (i < n) p[i] = 0.0f;
}
__global__ void zero_i(int* p, int n) {
    int i = blockIdx.x * blockDim.x + threadIdx.x;
    if (i < n) p[i] = 0;
}

// degf[c] += ew[e]; degi[c] += 1
__global__ void count_kernel(const int* __restrict__ col, const float* __restrict__ ew,
                             float* __restrict__ degf, int* __restrict__ degi, int E) {
    int e = blockIdx.x * blockDim.x + threadIdx.x;
    if (e >= E) return;
    int c = col[e];
    atomicAdd(&degf[c], ew[e]);
    atomicAdd(&degi[c], 1);
}

// dinv = rsqrt(degf + 1)   (+1 = self-loop weight; always > 0)
__global__ void dinv_kernel(float* __restrict__ degf, int n) {
    int i = blockIdx.x * blockDim.x + threadIdx.x;
    if (i < n) degf[i] = rsqrtf(degf[i] + 1.0f);
}

// ---- exclusive scan of degi -> rowptr ----
__global__ __launch_bounds__(256) void scan_bsum(const int* __restrict__ degi,
                                                 int* __restrict__ bsum, int n) {
    int base = blockIdx.x * 1024;
    int t = threadIdx.x;
    int s = 0;
    #pragma unroll
    for (int k = 0; k < 4; ++k) { int i = base + t * 4 + k; if (i < n) s += degi[i]; }
    __shared__ int sh[256];
    sh[t] = s; __syncthreads();
    for (int off = 128; off > 0; off >>= 1) {
        if (t < off) sh[t] += sh[t + off];
        __syncthreads();
    }
    if (t == 0) bsum[blockIdx.x] = sh[0];
}

__global__ void scan_exclusive_bsum(int* bsum, int nb) {
    if (blockIdx.x == 0 && threadIdx.x == 0) {
        int run = 0;
        for (int i = 0; i < nb; ++i) { int v = bsum[i]; bsum[i] = run; run += v; }
    }
}

__global__ __launch_bounds__(256) void scan_write_rowptr(const int* __restrict__ degi,
                                                         const int* __restrict__ bsum,
                                                         int* __restrict__ rowptr, int n, int E) {
    int base = blockIdx.x * 1024;
    int t = threadIdx.x;
    int v[4]; int s = 0;
    #pragma unroll
    for (int k = 0; k < 4; ++k) { int i = base + t * 4 + k; v[k] = (i < n) ? degi[i] : 0; s += v[k]; }
    __shared__ int sh[256];
    sh[t] = s; __syncthreads();
    for (int off = 1; off < 256; off <<= 1) {
        int x = (t >= off) ? sh[t - off] : 0;
        __syncthreads();
        sh[t] += x;
        __syncthreads();
    }
    int pre = bsum[blockIdx.x] + ((t > 0) ? sh[t - 1] : 0);
    #pragma unroll
    for (int k = 0; k < 4; ++k) { int i = base + t * 4 + k; if (i < n) rowptr[i] = pre; pre += v[k]; }
    if (blockIdx.x == 0 && t == 0) rowptr[n] = E;
}

// bin edges into CSR, packed entry {src, norm_weight}
__global__ void bin_kernel(const int* __restrict__ row, const int* __restrict__ col,
                           const float* __restrict__ ew, const float* __restrict__ dinv,
                           const int* __restrict__ rowptr, int* __restrict__ cursor,
                           int2* __restrict__ ent, int E) {
    int e = blockIdx.x * blockDim.x + threadIdx.x;
    if (e >= E) return;
    int r = row[e], c = col[e];
    int pos = rowptr[c] + atomicAdd(&cursor[c], 1);
    ent[pos] = make_int2(r, __float_as_int(dinv[r] * ew[e] * dinv[c]));
}

// y = x @ W^T : 512 thr/block, 128 rows/block; thread tile = 8 rows x 4 cols.
// cols j = jg + 32*jj (jg = lane%32) -> LDS W reads conflict-free with +1 pad.
#define GR 8
__global__ __launch_bounds__(512) void gemm_xwT(const float* __restrict__ X,
                                                const float* __restrict__ W,
                                                float* __restrict__ Y, int nrows) {
    __shared__ float Wl[D][D + 1];
    int tid = threadIdx.x;
    for (int i = tid; i < D * D; i += 512) Wl[i >> 7][i & 127] = W[i];
    __syncthreads();
    int jg = tid & 31;
    int rg = tid >> 5;                        // 0..15
    int row0 = blockIdx.x * 128 + rg * GR;
    const float4* X4 = reinterpret_cast<const float4*>(X);
    float acc[GR][4];
    #pragma unroll
    for (int i = 0; i < GR; ++i)
        #pragma unroll
        for (int jj = 0; jj < 4; ++jj) acc[i][jj] = 0.0f;

    bool full = (row0 + GR <= nrows);
    for (int d4 = 0; d4 < D; d4 += 4) {
        float4 xv[GR];
        if (full) {
            #pragma unroll
            for (int i = 0; i < GR; ++i)
                xv[i] = X4[((size_t)(row0 + i) * D + d4) >> 2];
        } else {
            #pragma unroll
            for (int i = 0; i < GR; ++i) {
                int r = row0 + i;
                xv[i] = (r < nrows) ? X4[((size_t)r * D + d4) >> 2]
                                    : make_float4(0.f, 0.f, 0.f, 0.f);
            }
        }
        #pragma unroll
        for (int dd = 0; dd < 4; ++dd) {
            int d = d4 + dd;
            float w[4];
            #pragma unroll
            for (int jj = 0; jj < 4; ++jj) w[jj] = Wl[jg + 32 * jj][d];
            #pragma unroll
            for (int i = 0; i < GR; ++i) {
                float xc = (dd == 0) ? xv[i].x : (dd == 1) ? xv[i].y
                         : (dd == 2) ? xv[i].z : xv[i].w;
                #pragma unroll
                for (int jj = 0; jj < 4; ++jj)
                    acc[i][jj] = fmaf(xc, w[jj], acc[i][jj]);
            }
        }
    }
    #pragma unroll
    for (int i = 0; i < GR; ++i) {
        int r = row0 + i;
        if (r < nrows) {
            #pragma unroll
            for (int jj = 0; jj < 4; ++jj)
                Y[(size_t)r * D + jg + 32 * jj] = acc[i][jj];
        }
    }
}

// gather: 32 lanes per node, float4/lane. out[n] = dinv[n]^2*h[n] + sum w_e h[src] (+bias)
__global__ __launch_bounds__(256) void hop_gather_kernel(
    const int* __restrict__ rowptr, const int2* __restrict__ ent,
    const float* __restrict__ dinv, const float* __restrict__ h,
    float* __restrict__ out, const float* __restrict__ bias, int N) {
    long long t = (long long)blockIdx.x * blockDim.x + threadIdx.x;
    int node = (int)(t >> 5);
    int lane = (int)(t & 31);
    if (node >= N) return;
    int beg = rowptr[node], end = rowptr[node + 1];
    float s = dinv[node];
    float ss = s * s;
    const float4* h4 = reinterpret_cast<const float4*>(h);
    float4 v = h4[(size_t)node * 32 + lane];
    float4 acc = make_float4(ss * v.x, ss * v.y, ss * v.z, ss * v.w);
    if (bias != nullptr) {
        float4 bv = reinterpret_cast<const float4*>(bias)[lane];
        acc.x += bv.x; acc.y += bv.y; acc.z += bv.z; acc.w += bv.w;
    }
    for (int base = beg; base < end; base += 32) {
        int cnt = min(32, end - base);
        int2 e = make_int2(0, 0);
        if (lane < cnt) e = ent[base + lane];
        for (int j = 0; j < cnt; ++j) {
            int   sj = __shfl(e.x, j, 32);
            float wj = __shfl(__int_as_float(e.y), j, 32);
            float4 hv = h4[(size_t)sj * 32 + lane];
            acc.x = fmaf(wj, hv.x, acc.x);
            acc.y = fmaf(wj, hv.y, acc.y);
            acc.z = fmaf(wj, hv.z, acc.z);
            acc.w = fmaf(wj, hv.w, acc.w);
        }
    }
    reinterpret_cast<float4*>(out)[(size_t)node * 32 + lane] = acc;
}

extern "C" void kernel_launch(void* const* d_in, const int* in_sizes, int n_in,
                              void* d_out, int out_size, void* d_ws, size_t ws_size,
                              hipStream_t stream) {
    const float* x    = (const float*)d_in[0];
    const int*   eidx = (const int*)d_in[1];
    const float* ew   = (const float*)d_in[2];
    const float* W    = (const float*)d_in[3];
    const float* bias = (const float*)d_in[4];
    float* out = (float*)d_out;

    const int N = in_sizes[0] / D;       // 100000
    const int E = in_sizes[2];           // 1600000
    const int* erow = eidx;              // sources
    const int* ecol = eidx + E;          // targets

    // ws layout (4B units): h1[N*D] | ent[2E] | dinv[N] | degi[N] | cursor[N] |
    //                       rowptr[N+1] | bsum[ceil(N/1024)]
    float* h1     = (float*)d_ws;
    int2*  ent    = (int2*)(h1 + (size_t)N * D);
    float* dinv   = (float*)(ent + E);
    int*   degi   = (int*)(dinv + N);
    int*   cursor = degi + N;
    int*   rowptr = cursor + N;
    int*   bsum   = rowptr + N + 1;

    const int B = 256;
    const int nb_scan = (N + 1023) / 1024;

    // 1. degree (weighted + count), dinv
    zero_f<<<(N + B - 1) / B, B, 0, stream>>>(dinv, N);        // dinv doubles as degf
    zero_i<<<(2 * N + B - 1) / B, B, 0, stream>>>(degi, 2 * N); // degi + cursor (adjacent)
    count_kernel<<<(E + B - 1) / B, B, 0, stream>>>(ecol, ew, dinv, degi, E);
    dinv_kernel<<<(N + B - 1) / B, B, 0, stream>>>(dinv, N);

    // 2. rowptr = exclusive_scan(degi)
    scan_bsum<<<nb_scan, 256, 0, stream>>>(degi, bsum, N);
    scan_exclusive_bsum<<<1, 1, 0, stream>>>(bsum, nb_scan);
    scan_write_rowptr<<<nb_scan, 256, 0, stream>>>(degi, bsum, rowptr, N, E);

    // 3. bin edges (packed {src, norm_w})
    bin_kernel<<<(E + B - 1) / B, B, 0, stream>>>(erow, ecol, ew, dinv, rowptr, cursor,
                                                  ent, E);

    // 4. y = x @ W^T  (into d_out as scratch)
    gemm_xwT<<<(N + 127) / 128, 512, 0, stream>>>(x, W, out, N);

    // 5. hop 1: h1 = A_hat y ; hop 2: out = A_hat h1 + bias
    const long long gthreads = (long long)N * 32;
    const int gblocks = (int)((gthreads + B - 1) / B);
    hop_gather_kernel<<<gblocks, B, 0, stream>>>(rowptr, ent, dinv, out, h1, nullptr, N);
    hop_gather_kernel<<<gblocks, B, 0, stream>>>(rowptr, ent, dinv, h1, out, bias, N);
}

// Round 6
// 588.872 us; speedup vs baseline: 9.7101x; 1.1105x over previous
//
#include <hip/hip_runtime.h>

// SGC: out = A_hat^2 (x @ W^T) + bias   (linear commutes with propagation)
// 1) y = x @ W^T          (GEMM, y lives in d_out as scratch)
// 2) h1 = A_hat y         (CSR gather, no atomics)
// 3) out = A_hat h1 + b   (CSR gather, bias fused)
// CSR build: packed u64 count atomics (4 replicas) -> scan -> bin.

constexpr int D = 128;

__global__ void zero_u64(unsigned long long* p, int n) {
    int i = blockIdx.x * blockDim.x + threadIdx.x;
    if (i < n) p[i] = 0ULL;
}

// one packed atomic per edge: (1<<40)|fix32(ew) into replica ((e>>6)&3)
__global__ void count_packed(const int* __restrict__ col, const float* __restrict__ ew,
                             unsigned long long* __restrict__ cnt4, int N, int E) {
    int e = blockIdx.x * blockDim.x + threadIdx.x;
    if (e >= E) return;
    int c = col[e];
    unsigned long long v = (1ULL << 40) |
        (unsigned long long)(ew[e] * 4294967296.0f);
    int rep = (e >> 6) & 3;
    atomicAdd(&cnt4[(size_t)rep * N + c], v);
}

// sum replicas -> dinv = rsqrt(deg+1), degi = count
__global__ void finalize_deg(const unsigned long long* __restrict__ cnt4,
                             float* __restrict__ dinv, int* __restrict__ degi, int N) {
    int i = blockIdx.x * blockDim.x + threadIdx.x;
    if (i >= N) return;
    unsigned long long s = cnt4[i] + cnt4[(size_t)N + i] +
                           cnt4[2 * (size_t)N + i] + cnt4[3 * (size_t)N + i];
    int cnt = (int)(s >> 40);
    float deg = (float)((double)(s & ((1ULL << 40) - 1)) * (1.0 / 4294967296.0));
    dinv[i] = rsqrtf(deg + 1.0f);
    degi[i] = cnt;
}

// ---- exclusive scan of degi -> rowptr ----
__global__ __launch_bounds__(256) void scan_bsum(const int* __restrict__ degi,
                                                 int* __restrict__ bsum, int n) {
    int base = blockIdx.x * 1024;
    int t = threadIdx.x;
    int s = 0;
    #pragma unroll
    for (int k = 0; k < 4; ++k) { int i = base + t * 4 + k; if (i < n) s += degi[i]; }
    __shared__ int sh[256];
    sh[t] = s; __syncthreads();
    for (int off = 128; off > 0; off >>= 1) {
        if (t < off) sh[t] += sh[t + off];
        __syncthreads();
    }
    if (t == 0) bsum[blockIdx.x] = sh[0];
}

__global__ void scan_exclusive_bsum(int* bsum, int nb) {
    if (blockIdx.x == 0 && threadIdx.x == 0) {
        int run = 0;
        for (int i = 0; i < nb; ++i) { int v = bsum[i]; bsum[i] = run; run += v; }
    }
}

__global__ __launch_bounds__(256) void scan_write_rowptr(const int* __restrict__ degi,
                                                         const int* __restrict__ bsum,
                                                         int* __restrict__ rowptr, int n, int E) {
    int base = blockIdx.x * 1024;
    int t = threadIdx.x;
    int v[4]; int s = 0;
    #pragma unroll
    for (int k = 0; k < 4; ++k) { int i = base + t * 4 + k; v[k] = (i < n) ? degi[i] : 0; s += v[k]; }
    __shared__ int sh[256];
    sh[t] = s; __syncthreads();
    for (int off = 1; off < 256; off <<= 1) {
        int x = (t >= off) ? sh[t - off] : 0;
        __syncthreads();
        sh[t] += x;
        __syncthreads();
    }
    int pre = bsum[blockIdx.x] + ((t > 0) ? sh[t - 1] : 0);
    #pragma unroll
    for (int k = 0; k < 4; ++k) { int i = base + t * 4 + k; if (i < n) rowptr[i] = pre; pre += v[k]; }
    if (blockIdx.x == 0 && t == 0) rowptr[n] = E;
}

__global__ void copy_cursor(const int* __restrict__ rowptr, int* __restrict__ cursor, int n) {
    int i = blockIdx.x * blockDim.x + threadIdx.x;
    if (i < n) cursor[i] = rowptr[i];
}

// bin edges into CSR, packed entry {src, norm_weight}; cursor pre-inited to rowptr
__global__ void bin_kernel(const int* __restrict__ row, const int* __restrict__ col,
                           const float* __restrict__ ew, const float* __restrict__ dinv,
                           int* __restrict__ cursor,
                           int2* __restrict__ ent, int E) {
    int e = blockIdx.x * blockDim.x + threadIdx.x;
    if (e >= E) return;
    int r = row[e], c = col[e];
    int pos = atomicAdd(&cursor[c], 1);
    ent[pos] = make_int2(r, __float_as_int(dinv[r] * ew[e] * dinv[c]));
}

// y = x @ W^T : 512 thr/block, 128 rows/block; thread tile = 8 rows x 4 cols.
#define GR 8
__global__ __launch_bounds__(512) void gemm_xwT(const float* __restrict__ X,
                                                const float* __restrict__ W,
                                                float* __restrict__ Y, int nrows) {
    __shared__ float Wl[D][D + 1];
    int tid = threadIdx.x;
    for (int i = tid; i < D * D; i += 512) Wl[i >> 7][i & 127] = W[i];
    __syncthreads();
    int jg = tid & 31;
    int rg = tid >> 5;                        // 0..15
    int row0 = blockIdx.x * 128 + rg * GR;
    const float4* X4 = reinterpret_cast<const float4*>(X);
    float acc[GR][4];
    #pragma unroll
    for (int i = 0; i < GR; ++i)
        #pragma unroll
        for (int jj = 0; jj < 4; ++jj) acc[i][jj] = 0.0f;

    bool full = (row0 + GR <= nrows);
    for (int d4 = 0; d4 < D; d4 += 4) {
        float4 xv[GR];
        if (full) {
            #pragma unroll
            for (int i = 0; i < GR; ++i)
                xv[i] = X4[((size_t)(row0 + i) * D + d4) >> 2];
        } else {
            #pragma unroll
            for (int i = 0; i < GR; ++i) {
                int r = row0 + i;
                xv[i] = (r < nrows) ? X4[((size_t)r * D + d4) >> 2]
                                    : make_float4(0.f, 0.f, 0.f, 0.f);
            }
        }
        #pragma unroll
        for (int dd = 0; dd < 4; ++dd) {
            int d = d4 + dd;
            float w[4];
            #pragma unroll
            for (int jj = 0; jj < 4; ++jj) w[jj] = Wl[jg + 32 * jj][d];
            #pragma unroll
            for (int i = 0; i < GR; ++i) {
                float xc = (dd == 0) ? xv[i].x : (dd == 1) ? xv[i].y
                         : (dd == 2) ? xv[i].z : xv[i].w;
                #pragma unroll
                for (int jj = 0; jj < 4; ++jj)
                    acc[i][jj] = fmaf(xc, w[jj], acc[i][jj]);
            }
        }
    }
    #pragma unroll
    for (int i = 0; i < GR; ++i) {
        int r = row0 + i;
        if (r < nrows) {
            #pragma unroll
            for (int jj = 0; jj < 4; ++jj)
                Y[(size_t)r * D + jg + 32 * jj] = acc[i][jj];
        }
    }
}

// gather: 32 lanes per node, float4/lane. out[n] = dinv[n]^2*h[n] + sum w_e h[src] (+bias)
__global__ __launch_bounds__(256) void hop_gather_kernel(
    const int* __restrict__ rowptr, const int2* __restrict__ ent,
    const float* __restrict__ dinv, const float* __restrict__ h,
    float* __restrict__ out, const float* __restrict__ bias, int N) {
    long long t = (long long)blockIdx.x * blockDim.x + threadIdx.x;
    int node = (int)(t >> 5);
    int lane = (int)(t & 31);
    if (node >= N) return;
    int beg = rowptr[node], end = rowptr[node + 1];
    float s = dinv[node];
    float ss = s * s;
    const float4* h4 = reinterpret_cast<const float4*>(h);
    float4 v = h4[(size_t)node * 32 + lane];
    float4 acc = make_float4(ss * v.x, ss * v.y, ss * v.z, ss * v.w);
    if (bias != nullptr) {
        float4 bv = reinterpret_cast<const float4*>(bias)[lane];
        acc.x += bv.x; acc.y += bv.y; acc.z += bv.z; acc.w += bv.w;
    }
    for (int base = beg; base < end; base += 32) {
        int cnt = min(32, end - base);
        int2 e = make_int2(0, 0);
        if (lane < cnt) e = ent[base + lane];
        for (int j = 0; j < cnt; ++j) {
            int   sj = __shfl(e.x, j, 32);
            float wj = __shfl(__int_as_float(e.y), j, 32);
            float4 hv = h4[(size_t)sj * 32 + lane];
            acc.x = fmaf(wj, hv.x, acc.x);
            acc.y = fmaf(wj, hv.y, acc.y);
            acc.z = fmaf(wj, hv.z, acc.z);
            acc.w = fmaf(wj, hv.w, acc.w);
        }
    }
    reinterpret_cast<float4*>(out)[(size_t)node * 32 + lane] = acc;
}

extern "C" void kernel_launch(void* const* d_in, const int* in_sizes, int n_in,
                              void* d_out, int out_size, void* d_ws, size_t ws_size,
                              hipStream_t stream) {
    const float* x    = (const float*)d_in[0];
    const int*   eidx = (const int*)d_in[1];
    const float* ew   = (const float*)d_in[2];
    const float* W    = (const float*)d_in[3];
    const float* bias = (const float*)d_in[4];
    float* out = (float*)d_out;

    const int N = in_sizes[0] / D;       // 100000
    const int E = in_sizes[2];           // 1600000
    const int* erow = eidx;              // sources
    const int* ecol = eidx + E;          // targets

    // ws layout (4B units): h1[N*D] (cnt4[4N u64] aliased at start — dead before h1
    // is written) | ent[2E] | dinv[N] | degi[N] | cursor[N] | rowptr[N+1] | bsum
    float* h1     = (float*)d_ws;
    unsigned long long* cnt4 = (unsigned long long*)d_ws;   // alias, used only pre-h1
    int2*  ent    = (int2*)(h1 + (size_t)N * D);
    float* dinv   = (float*)(ent + E);
    int*   degi   = (int*)(dinv + N);
    int*   cursor = degi + N;
    int*   rowptr = cursor + N;
    int*   bsum   = rowptr + N + 1;

    const int B = 256;
    const int nb_scan = (N + 1023) / 1024;

    // 1. packed degree histogram (4 replicas), finalize -> dinv, degi
    zero_u64<<<(4 * N + B - 1) / B, B, 0, stream>>>(cnt4, 4 * N);
    count_packed<<<(E + B - 1) / B, B, 0, stream>>>(ecol, ew, cnt4, N, E);
    finalize_deg<<<(N + B - 1) / B, B, 0, stream>>>(cnt4, dinv, degi, N);

    // 2. rowptr = exclusive_scan(degi); cursor = rowptr
    scan_bsum<<<nb_scan, 256, 0, stream>>>(degi, bsum, N);
    scan_exclusive_bsum<<<1, 1, 0, stream>>>(bsum, nb_scan);
    scan_write_rowptr<<<nb_scan, 256, 0, stream>>>(degi, bsum, rowptr, N, E);
    copy_cursor<<<(N + B - 1) / B, B, 0, stream>>>(rowptr, cursor, N);

    // 3. bin edges (packed {src, norm_w})
    bin_kernel<<<(E + B - 1) / B, B, 0, stream>>>(erow, ecol, ew, dinv, cursor, ent, E);

    // 4. y = x @ W^T  (into d_out as scratch)
    gemm_xwT<<<(N + 127) / 128, 512, 0, stream>>>(x, W, out, N);

    // 5. hop 1: h1 = A_hat y ; hop 2: out = A_hat h1 + bias
    const long long gthreads = (long long)N * 32;
    const int gblocks = (int)((gthreads + B - 1) / B);
    hop_gather_kernel<<<gblocks, B, 0, stream>>>(rowptr, ent, dinv, out, h1, nullptr, N);
    hop_gather_kernel<<<gblocks, B, 0, stream>>>(rowptr, ent, dinv, h1, out, bias, N);
}

// Round 9
// 517.732 us; speedup vs baseline: 11.0444x; 1.1374x over previous
//
#include <hip/hip_runtime.h>
#include <hip/hip_bf16.h>

// SGC: out = A_hat^2 (x @ W^T) + bias   (linear commutes with propagation)
// 1) y = x @ W^T           (GEMM, y stored as bf16 in ws)
// 2) h1 = A_hat y          (CSR gather, bf16 in / bf16 out, f32 accum)
// 3) out = A_hat h1 + b    (CSR gather, bf16 in / f32 out, bias fused)
// CSR build: packed u64 histogram [node][rep] (4 reps) -> scan(4N) -> bin
// with per-(node,rep) cursors (4-way lower atomic contention).

constexpr int D = 128;

__global__ void zero_u64(unsigned long long* p, int n) {
    int i = blockIdx.x * blockDim.x + threadIdx.x;
    if (i < n) p[i] = 0ULL;
}

// one packed atomic per edge: (1<<40)|fix32(ew) into cnt4[col*4 + rep]
__global__ void count_packed(const int* __restrict__ col, const float* __restrict__ ew,
                             unsigned long long* __restrict__ cnt4, int E) {
    int e = blockIdx.x * blockDim.x + threadIdx.x;
    if (e >= E) return;
    int c = col[e];
    unsigned long long v = (1ULL << 40) |
        (unsigned long long)(ew[e] * 4294967296.0f);
    int rep = (e >> 6) & 3;
    atomicAdd(&cnt4[(size_t)c * 4 + rep], v);
}

// dinv = rsqrt(sum_rep weighted + 1)
__global__ void finalize_deg(const unsigned long long* __restrict__ cnt4,
                             float* __restrict__ dinv, int N) {
    int i = blockIdx.x * blockDim.x + threadIdx.x;
    if (i >= N) return;
    const unsigned long long* p = cnt4 + (size_t)i * 4;
    unsigned long long s = p[0] + p[1] + p[2] + p[3];
    float deg = (float)((double)(s & ((1ULL << 40) - 1)) * (1.0 / 4294967296.0));
    dinv[i] = rsqrtf(deg + 1.0f);
}

// ---- exclusive scan over 4N bucket counts (cnt4[i]>>40) -> rowptr4 ----
__global__ __launch_bounds__(256) void scan_bsum(const unsigned long long* __restrict__ cnt,
                                                 int* __restrict__ bsum, int n) {
    int base = blockIdx.x * 1024;
    int t = threadIdx.x;
    int s = 0;
    #pragma unroll
    for (int k = 0; k < 4; ++k) { int i = base + t * 4 + k; if (i < n) s += (int)(cnt[i] >> 40); }
    __shared__ int sh[256];
    sh[t] = s; __syncthreads();
    for (int off = 128; off > 0; off >>= 1) {
        if (t < off) sh[t] += sh[t + off];
        __syncthreads();
    }
    if (t == 0) bsum[blockIdx.x] = sh[0];
}

__global__ void scan_exclusive_bsum(int* bsum, int nb) {
    if (blockIdx.x == 0 && threadIdx.x == 0) {
        int run = 0;
        for (int i = 0; i < nb; ++i) { int v = bsum[i]; bsum[i] = run; run += v; }
    }
}

__global__ __launch_bounds__(256) void scan_write_rowptr(const unsigned long long* __restrict__ cnt,
                                                         const int* __restrict__ bsum,
                                                         int* __restrict__ rowptr4, int n) {
    int base = blockIdx.x * 1024;
    int t = threadIdx.x;
    int v[4]; int s = 0;
    #pragma unroll
    for (int k = 0; k < 4; ++k) { int i = base + t * 4 + k; v[k] = (i < n) ? (int)(cnt[i] >> 40) : 0; s += v[k]; }
    __shared__ int sh[256];
    sh[t] = s; __syncthreads();
    for (int off = 1; off < 256; off <<= 1) {
        int x = (t >= off) ? sh[t - off] : 0;
        __syncthreads();
        sh[t] += x;
        __syncthreads();
    }
    int pre = bsum[blockIdx.x] + ((t > 0) ? sh[t - 1] : 0);
    #pragma unroll
    for (int k = 0; k < 4; ++k) { int i = base + t * 4 + k; if (i < n) rowptr4[i] = pre; pre += v[k]; }
}

// compact per-node rowptr for the gather: rowptr[n] = rowptr4[4n], rowptr[N] = E
__global__ void compact_rowptr(const int* __restrict__ rowptr4, int* __restrict__ rowptr,
                               int N, int E) {
    int i = blockIdx.x * blockDim.x + threadIdx.x;
    if (i < N) rowptr[i] = rowptr4[i * 4];
    if (i == N) rowptr[N] = E;
}

// bin edges into CSR; rowptr4 is consumed destructively as the cursor array
__global__ void bin_kernel(const int* __restrict__ row, const int* __restrict__ col,
                           const float* __restrict__ ew, const float* __restrict__ dinv,
                           int* __restrict__ cursor4,
                           int2* __restrict__ ent, int E) {
    int e = blockIdx.x * blockDim.x + threadIdx.x;
    if (e >= E) return;
    int r = row[e], c = col[e];
    int rep = (e >> 6) & 3;
    int pos = atomicAdd(&cursor4[(size_t)c * 4 + rep], 1);
    ent[pos] = make_int2(r, __float_as_int(dinv[r] * ew[e] * dinv[c]));
}

// y = x @ W^T -> bf16 : 512 thr/block, 128 rows/block; thread tile 8 rows x 4 cols.
#define GR 8
__global__ __launch_bounds__(512) void gemm_xwT_bf16(const float* __restrict__ X,
                                                     const float* __restrict__ W,
                                                     unsigned short* __restrict__ Yb, int nrows) {
    __shared__ float Wl[D][D + 1];
    int tid = threadIdx.x;
    for (int i = tid; i < D * D; i += 512) Wl[i >> 7][i & 127] = W[i];
    __syncthreads();
    int jg = tid & 31;
    int rg = tid >> 5;                        // 0..15
    int row0 = blockIdx.x * 128 + rg * GR;
    const float4* X4 = reinterpret_cast<const float4*>(X);
    float acc[GR][4];
    #pragma unroll
    for (int i = 0; i < GR; ++i)
        #pragma unroll
        for (int jj = 0; jj < 4; ++jj) acc[i][jj] = 0.0f;

    bool full = (row0 + GR <= nrows);
    for (int d4 = 0; d4 < D; d4 += 4) {
        float4 xv[GR];
        if (full) {
            #pragma unroll
            for (int i = 0; i < GR; ++i)
                xv[i] = X4[((size_t)(row0 + i) * D + d4) >> 2];
        } else {
            #pragma unroll
            for (int i = 0; i < GR; ++i) {
                int r = row0 + i;
                xv[i] = (r < nrows) ? X4[((size_t)r * D + d4) >> 2]
                                    : make_float4(0.f, 0.f, 0.f, 0.f);
            }
        }
        #pragma unroll
        for (int dd = 0; dd < 4; ++dd) {
            int d = d4 + dd;
            float w[4];
            #pragma unroll
            for (int jj = 0; jj < 4; ++jj) w[jj] = Wl[jg + 32 * jj][d];
            #pragma unroll
            for (int i = 0; i < GR; ++i) {
                float xc = (dd == 0) ? xv[i].x : (dd == 1) ? xv[i].y
                         : (dd == 2) ? xv[i].z : xv[i].w;
                #pragma unroll
                for (int jj = 0; jj < 4; ++jj)
                    acc[i][jj] = fmaf(xc, w[jj], acc[i][jj]);
            }
        }
    }
    #pragma unroll
    for (int i = 0; i < GR; ++i) {
        int r = row0 + i;
        if (r < nrows) {
            #pragma unroll
            for (int jj = 0; jj < 4; ++jj) {
                __hip_bfloat16 hv = __float2bfloat16(acc[i][jj]);
                Yb[(size_t)r * D + jg + 32 * jj] = *reinterpret_cast<unsigned short*>(&hv);
            }
        }
    }
}

__device__ __forceinline__ float bf_lo(unsigned int u) { return __uint_as_float(u << 16); }
__device__ __forceinline__ float bf_hi(unsigned int u) { return __uint_as_float(u & 0xffff0000u); }

// gather (bf16 rows): 32 lanes/node, uint2 (4 bf16)/lane, f32 accum.
// outf != null: write f32 (+bias). else write bf16 to outb.
__global__ __launch_bounds__(256) void hop_gather_bf16(
    const int* __restrict__ rowptr, const int2* __restrict__ ent,
    const float* __restrict__ dinv, const unsigned short* __restrict__ h,
    float* __restrict__ outf, unsigned short* __restrict__ outb,
    const float* __restrict__ bias, int N) {
    long long t = (long long)blockIdx.x * blockDim.x + threadIdx.x;
    int node = (int)(t >> 5);
    int lane = (int)(t & 31);
    if (node >= N) return;
    int beg = rowptr[node], end = rowptr[node + 1];
    float s = dinv[node];
    float ss = s * s;
    const uint2* h2 = reinterpret_cast<const uint2*>(h);   // 8B = 4 bf16 per lane
    uint2 sv = h2[(size_t)node * 32 + lane];
    float4 acc = make_float4(ss * bf_lo(sv.x), ss * bf_hi(sv.x),
                             ss * bf_lo(sv.y), ss * bf_hi(sv.y));
    if (bias != nullptr) {
        float4 bv = reinterpret_cast<const float4*>(bias)[lane];
        acc.x += bv.x; acc.y += bv.y; acc.z += bv.z; acc.w += bv.w;
    }
    for (int base = beg; base < end; base += 32) {
        int cnt = min(32, end - base);
        int2 e = make_int2(0, 0);
        if (lane < cnt) e = ent[base + lane];
        for (int j = 0; j < cnt; ++j) {
            int   sj = __shfl(e.x, j, 32);
            float wj = __shfl(__int_as_float(e.y), j, 32);
            uint2 hv = h2[(size_t)sj * 32 + lane];
            acc.x = fmaf(wj, bf_lo(hv.x), acc.x);
            acc.y = fmaf(wj, bf_hi(hv.x), acc.y);
            acc.z = fmaf(wj, bf_lo(hv.y), acc.z);
            acc.w = fmaf(wj, bf_hi(hv.y), acc.w);
        }
    }
    if (outf != nullptr) {
        reinterpret_cast<float4*>(outf)[(size_t)node * 32 + lane] = acc;
    } else {
        __hip_bfloat16 b0 = __float2bfloat16(acc.x);
        __hip_bfloat16 b1 = __float2bfloat16(acc.y);
        __hip_bfloat16 b2 = __float2bfloat16(acc.z);
        __hip_bfloat16 b3 = __float2bfloat16(acc.w);
        uint2 pk;
        pk.x = (unsigned int)*reinterpret_cast<unsigned short*>(&b0) |
               ((unsigned int)*reinterpret_cast<unsigned short*>(&b1) << 16);
        pk.y = (unsigned int)*reinterpret_cast<unsigned short*>(&b2) |
               ((unsigned int)*reinterpret_cast<unsigned short*>(&b3) << 16);
        reinterpret_cast<uint2*>(outb)[(size_t)node * 32 + lane] = pk;
    }
}

extern "C" void kernel_launch(void* const* d_in, const int* in_sizes, int n_in,
                              void* d_out, int out_size, void* d_ws, size_t ws_size,
                              hipStream_t stream) {
    const float* x    = (const float*)d_in[0];
    const int*   eidx = (const int*)d_in[1];
    const float* ew   = (const float*)d_in[2];
    const float* W    = (const float*)d_in[3];
    const float* bias = (const float*)d_in[4];
    float* out = (float*)d_out;

    const int N = in_sizes[0] / D;       // 100000
    const int E = in_sizes[2];           // 1600000
    const int* erow = eidx;              // sources
    const int* ecol = eidx + E;          // targets

    // ws layout (4B words):  [bf16 row = 256B = 64 words]
    //   yb  : N*64 words (bf16 y, 25.6MB)   — cnt4[4N u64 = 3.2MB] aliases (dead pre-gemm)
    //   h1b : N*64 words (bf16 h1, 25.6MB)  — rowptr4[4N]+bsum alias (dead pre-gather1)
    //   ent : E int2 (12.8MB)
    //   dinv: N f32
    //   rowptr: N+1 int
    unsigned int* yb  = (unsigned int*)d_ws;
    unsigned int* h1b = yb + (size_t)N * 64;            // N*128 bf16 = N*64 words
    int2*  ent    = (int2*)(h1b + (size_t)N * 64);
    float* dinv   = (float*)(ent + E);
    int*   rowptr = (int*)(dinv + N);

    unsigned long long* cnt4 = (unsigned long long*)yb;   // alias (pre-gemm only)
    int* rowptr4 = (int*)h1b;                             // alias (pre-gather1 only)
    int* bsum    = rowptr4 + 4 * N + 4;                   // alias, after rowptr4

    const int B = 256;
    const int M = 4 * N;                  // bucket count
    const int nb_scan = (M + 1023) / 1024;

    // 1. packed per-(node,rep) histogram -> dinv
    zero_u64<<<(M + B - 1) / B, B, 0, stream>>>(cnt4, M);
    count_packed<<<(E + B - 1) / B, B, 0, stream>>>(ecol, ew, cnt4, E);
    finalize_deg<<<(N + B - 1) / B, B, 0, stream>>>(cnt4, dinv, N);

    // 2. rowptr4 = exclusive_scan(bucket counts); compact per-node rowptr
    scan_bsum<<<nb_scan, 256, 0, stream>>>(cnt4, bsum, M);
    scan_exclusive_bsum<<<1, 1, 0, stream>>>(bsum, nb_scan);
    scan_write_rowptr<<<nb_scan, 256, 0, stream>>>(cnt4, bsum, rowptr4, M);
    compact_rowptr<<<(N + 1 + B - 1) / B, B, 0, stream>>>(rowptr4, rowptr, N, E);

    // 3. bin edges (rowptr4 consumed as cursors, 4-way contention)
    bin_kernel<<<(E + B - 1) / B, B, 0, stream>>>(erow, ecol, ew, dinv, rowptr4, ent, E);

    // 4. y = x @ W^T (bf16, clobbers cnt4 alias — safe: scan done)
    gemm_xwT_bf16<<<(N + 127) / 128, 512, 0, stream>>>(x, W, (unsigned short*)yb, N);

    // 5. hop 1: h1b = A_hat y (bf16->bf16, clobbers rowptr4 alias — safe: bin done)
    //    hop 2: out = A_hat h1b + bias (bf16->f32)
    const long long gthreads = (long long)N * 32;
    const int gblocks = (int)((gthreads + B - 1) / B);
    hop_gather_bf16<<<gblocks, B, 0, stream>>>(rowptr, ent, dinv, (unsigned short*)yb,
                                               nullptr, (unsigned short*)h1b, nullptr, N);
    hop_gather_bf16<<<gblocks, B, 0, stream>>>(rowptr, ent, dinv, (unsigned short*)h1b,
                                               out, nullptr, bias, N);
}